// Round 2
// baseline (368.009 us; speedup 1.0000x reference)
//
#include <hip/hip_runtime.h>
#include <cstdint>
#include <cmath>

#define NE 320000
#define NN 20000
#define NG 64

typedef __attribute__((ext_vector_type(8))) short s16x8;
typedef __attribute__((ext_vector_type(4))) float f32x4;

static __device__ __forceinline__ unsigned short f32_to_bf16(float x) {
    unsigned int u = __float_as_uint(x);
    u = (u + 0x7fffu + ((u >> 16) & 1u)) >> 16;
    return (unsigned short)u;
}
static __device__ __forceinline__ float bf16_to_f32(unsigned short h) {
    return __uint_as_float(((unsigned int)h) << 16);
}

// ---------------------------------------------------------------------------
// Prep: transpose + bf16 hi/lo split of w_r2 m=0 slices, both layers.
// Wt[c][k] (c in [0,64): c<32 -> layer0 col c, c>=32 -> layer1 col c-32)
// ---------------------------------------------------------------------------
__global__ __launch_bounds__(256) void prep_w_kernel(
    const float* __restrict__ w_r2,
    unsigned short* __restrict__ wt_hi, unsigned short* __restrict__ wt_lo)
{
    int t = blockIdx.x * 256 + threadIdx.x;   // 4096 entries
    int c = t >> 6, k = t & 63;
    float v = w_r2[(c >= 32 ? 6144 : 0) + k * 96 + (c & 31)];
    unsigned short hb = f32_to_bf16(v);
    float lov = v - bf16_to_f32(hb);
    wt_hi[t] = hb;
    wt_lo[t] = f32_to_bf16(lov);
}

// ---------------------------------------------------------------------------
// Fused edge kernel: bessel -> silu MLP -> (LDS bf16 hi/lo) -> MFMA GEMM
// against Wt (64x64, both layers) -> rw0_0[E][32], rw0_1[E][32] f32.
// Block = 256 threads = 4 waves = 256 edges.
// ---------------------------------------------------------------------------
__global__ __launch_bounds__(256) void edge_gemm_kernel(
    const float* __restrict__ vectors,
    const float* __restrict__ w_r1,    // 8 x 64
    const float* __restrict__ b_r1,    // 64
    const unsigned short* __restrict__ wt_hi,  // [64][64] bf16
    const unsigned short* __restrict__ wt_lo,  // [64][64] bf16
    float* __restrict__ rw0_0,         // [E][32]
    float* __restrict__ rw0_1)         // [E][32]
{
    // padded stride 72 shorts = 144 B (kills stride-128B bank conflicts)
    __shared__ __attribute__((aligned(16))) short sh_hi[256 * 72];
    __shared__ __attribute__((aligned(16))) short sh_lo[256 * 72];

    const int tid = threadIdx.x;
    const int e = blockIdx.x * 256 + tid;

    // ---- phase 1: radial features for this thread's edge ----
    float x = vectors[3 * e + 0];
    float y = vectors[3 * e + 1];
    float z = vectors[3 * e + 2];
    float r2 = x * x + y * y + z * z;
    float r = (r2 == 0.0f) ? 0.0f : sqrtf(r2);
    float rs = fmaxf(r, 1e-6f);
    float u = fminf(r * 0.2f, 1.0f);
    float env = (1.0f - u) * (1.0f - u) * (1.0f + 2.0f * u);
    float pref = 0.6324555320336759f * env / rs;   // sqrt(2/5)*env/rs
    float theta = 0.6283185307179586f * rs;        // pi/5 * rs

    float s1 = __sinf(theta), c1 = __cosf(theta);
    float twoc = 2.0f * c1;
    float b[8];
    {
        float sp = 0.0f, s = s1;
#pragma unroll
        for (int n = 0; n < 8; ++n) {
            b[n] = pref * s;
            float nx = twoc * s - sp;
            sp = s; s = nx;
        }
    }

#pragma unroll
    for (int j0 = 0; j0 < 64; j0 += 8) {
        short hibuf[8], lobuf[8];
#pragma unroll
        for (int jj = 0; jj < 8; ++jj) {
            int j = j0 + jj;
            float pre = b_r1[j];
#pragma unroll
            for (int n = 0; n < 8; ++n) pre = fmaf(b[n], w_r1[n * 64 + j], pre);
            float rj = pre * __builtin_amdgcn_rcpf(1.0f + __expf(-pre));
            unsigned short hb = f32_to_bf16(rj);
            float lov = rj - bf16_to_f32(hb);
            hibuf[jj] = (short)hb;
            lobuf[jj] = (short)f32_to_bf16(lov);
        }
        *(s16x8*)&sh_hi[tid * 72 + j0] =
            (s16x8){hibuf[0],hibuf[1],hibuf[2],hibuf[3],hibuf[4],hibuf[5],hibuf[6],hibuf[7]};
        *(s16x8*)&sh_lo[tid * 72 + j0] =
            (s16x8){lobuf[0],lobuf[1],lobuf[2],lobuf[3],lobuf[4],lobuf[5],lobuf[6],lobuf[7]};
    }

    __syncthreads();

    // ---- phase 2: MFMA. wave w owns rows w*64..w*64+63 ----
    const int wv = tid >> 6;
    const int l = tid & 63;
    const int lrow = l & 15;
    const int lk = l >> 4;          // k-group 0..3

    // B fragments (both precisions), ct = col-tile 0..3, kt = k-tile 0..1
    s16x8 Bhi[4][2], Blo[4][2];
#pragma unroll
    for (int ct = 0; ct < 4; ++ct)
#pragma unroll
        for (int kt = 0; kt < 2; ++kt) {
            int col = ct * 16 + lrow;
            int kof = kt * 32 + lk * 8;
            Bhi[ct][kt] = *(const s16x8*)(wt_hi + col * 64 + kof);
            Blo[ct][kt] = *(const s16x8*)(wt_lo + col * 64 + kof);
        }

    f32x4 acc[4][4];
#pragma unroll
    for (int rt = 0; rt < 4; ++rt)
#pragma unroll
        for (int ct = 0; ct < 4; ++ct) acc[rt][ct] = (f32x4){0.f, 0.f, 0.f, 0.f};

#pragma unroll
    for (int rt = 0; rt < 4; ++rt) {
        int row = wv * 64 + rt * 16 + lrow;
#pragma unroll
        for (int kt = 0; kt < 2; ++kt) {
            s16x8 ahi = *(const s16x8*)&sh_hi[row * 72 + kt * 32 + lk * 8];
            s16x8 alo = *(const s16x8*)&sh_lo[row * 72 + kt * 32 + lk * 8];
#pragma unroll
            for (int ct = 0; ct < 4; ++ct) {
                acc[rt][ct] = __builtin_amdgcn_mfma_f32_16x16x32_bf16(ahi, Bhi[ct][kt], acc[rt][ct], 0, 0, 0);
                acc[rt][ct] = __builtin_amdgcn_mfma_f32_16x16x32_bf16(alo, Bhi[ct][kt], acc[rt][ct], 0, 0, 0);
                acc[rt][ct] = __builtin_amdgcn_mfma_f32_16x16x32_bf16(ahi, Blo[ct][kt], acc[rt][ct], 0, 0, 0);
            }
        }
    }

    // ---- phase 3: store. D: col = ct*16 + (l&15), row = rt*16 + (l>>4)*4 + r
#pragma unroll
    for (int rt = 0; rt < 4; ++rt) {
#pragma unroll
        for (int ct = 0; ct < 4; ++ct) {
            int ebase = blockIdx.x * 256 + wv * 64 + rt * 16 + lk * 4;
            int col = ct * 16 + lrow;
            float* base = (col < 32) ? (rw0_0 + col) : (rw0_1 + (col - 32));
#pragma unroll
            for (int rr = 0; rr < 4; ++rr)
                base[(size_t)(ebase + rr) * 32] = acc[rt][ct][rr];
        }
    }
}

// ---------------------------------------------------------------------------
__global__ __launch_bounds__(256) void init_h_kernel(
    const int* __restrict__ spec, const float* __restrict__ emb,
    float* __restrict__ h, int N)
{
    int t = blockIdx.x * 256 + threadIdx.x;
    if (t >= N * 32) return;
    int n = t >> 5, c = t & 31;
    h[t] = emb[spec[n] * 32 + c];
}

// ---------------------------------------------------------------------------
// message: thread = (edge, quad of 4 channels). 4 atomics per thread.
// ---------------------------------------------------------------------------
__global__ __launch_bounds__(256) void message_kernel(
    const float* __restrict__ rw0, const float* __restrict__ h,
    const int* __restrict__ senders, const int* __restrict__ receivers,
    float* __restrict__ agg, int E)
{
    int idx = blockIdx.x * 256 + threadIdx.x;
    int e = idx >> 3, q = idx & 7;
    int s = senders[e];
    int rcv = receivers[e];
    float4 rv = *(const float4*)(rw0 + (size_t)e * 32 + q * 4);
    float4 hv = *(const float4*)(h + (size_t)s * 32 + q * 4);
    float* dst = agg + (size_t)rcv * 32 + q * 4;
    atomicAdd(dst + 0, rv.x * hv.x);
    atomicAdd(dst + 1, rv.y * hv.y);
    atomicAdd(dst + 2, rv.z * hv.z);
    atomicAdd(dst + 3, rv.w * hv.w);
}

// ---------------------------------------------------------------------------
__global__ __launch_bounds__(256) void update_kernel(
    const float* __restrict__ agg, const float* __restrict__ h_in,
    const int* __restrict__ spec,
    const float* __restrict__ w_mix0,  // 32 x 32
    const float* __restrict__ w_sc_l,  // 64 x 32 x 32
    float* __restrict__ h_out, int N)
{
    int t = blockIdx.x * 256 + threadIdx.x;
    if (t >= N * 32) return;
    int n = t >> 5, d = t & 31;
    int s = spec[n];
    const float* wsc = w_sc_l + s * 1024 + d;
    const float* wmx = w_mix0 + d;
    const float* ag = agg + (size_t)n * 32;
    const float* hi = h_in + (size_t)n * 32;
    float acc = hi[d];
#pragma unroll
    for (int c = 0; c < 32; ++c) {
        acc = fmaf(ag[c], wmx[c * 32], acc);
        acc = fmaf(hi[c], wsc[c * 32], acc);
    }
    h_out[t] = acc;
}

// ---------------------------------------------------------------------------
__global__ __launch_bounds__(256) void readout_kernel(
    const float* __restrict__ h, const int* __restrict__ gid_arr,
    const float* __restrict__ w_ro,
    const float* __restrict__ gamma, const float* __restrict__ beta,
    const float* __restrict__ w_h1, const float* __restrict__ b_h1,
    const float* __restrict__ w_h2, const float* __restrict__ b_h2,
    float* __restrict__ gsum, float* __restrict__ gcnt, int N)
{
    int t = blockIdx.x * 256 + threadIdx.x;
    int lane = threadIdx.x & 63;
    bool active = t < N;

    float val = 0.0f;
    int gid = -1;
    if (active) {
        gid = gid_arr[t];
        const float* hr = h + (size_t)t * 32;
        float ro[16];
#pragma unroll
        for (int o = 0; o < 16; ++o) ro[o] = 0.0f;
#pragma unroll
        for (int c = 0; c < 32; ++c) {
            float hv = hr[c];
#pragma unroll
            for (int o = 0; o < 16; ++o) ro[o] = fmaf(hv, w_ro[c * 16 + o], ro[o]);
        }
        float mu = 0.0f;
#pragma unroll
        for (int o = 0; o < 16; ++o) mu += ro[o];
        mu *= (1.0f / 16.0f);
        float var = 0.0f;
#pragma unroll
        for (int o = 0; o < 16; ++o) { float d = ro[o] - mu; var = fmaf(d, d, var); }
        var *= (1.0f / 16.0f);
        float inv = rsqrtf(var + 1e-6f);
        float nrm[16];
#pragma unroll
        for (int o = 0; o < 16; ++o) nrm[o] = (ro[o] - mu) * inv * gamma[o] + beta[o];

        float outv = b_h2[0];
        for (int j = 0; j < 64; ++j) {
            float a = b_h1[j];
#pragma unroll
            for (int o = 0; o < 16; ++o) a = fmaf(nrm[o], w_h1[o * 64 + j], a);
            float g = 0.5f * a * (1.0f + tanhf(0.7978845608028654f * (a + 0.044715f * a * a * a)));
            outv = fmaf(g, w_h2[j], outv);
        }
        val = outv;
    }
    float cval = active ? 1.0f : 0.0f;

#pragma unroll
    for (int off = 1; off < 64; off <<= 1) {
        float v = __shfl_down(val, off);
        float cv = __shfl_down(cval, off);
        int g = __shfl_down(gid, off);
        if (lane + off < 64 && g == gid) { val += v; cval += cv; }
    }
    int gprev = __shfl_up(gid, 1);
    bool head = (lane == 0) || (gprev != gid);
    if (active && head) {
        atomicAdd(&gsum[gid], val);
        atomicAdd(&gcnt[gid], cval);
    }
}

// ---------------------------------------------------------------------------
__global__ void finalize_kernel(const float* __restrict__ gsum,
                                const float* __restrict__ gcnt,
                                const float* __restrict__ scale,
                                const float* __restrict__ shift,
                                float* __restrict__ out, int G)
{
    int g = blockIdx.x * blockDim.x + threadIdx.x;
    if (g < G) out[g] = gsum[g] / fmaxf(gcnt[g], 1.0f) * scale[0] + shift[0];
}

// ---------------------------------------------------------------------------
extern "C" void kernel_launch(void* const* d_in, const int* in_sizes, int n_in,
                              void* d_out, int out_size, void* d_ws, size_t ws_size,
                              hipStream_t stream)
{
    const float* vectors       = (const float*)d_in[0];
    const int*   node_species  = (const int*)d_in[1];
    const int*   senders       = (const int*)d_in[2];
    const int*   receivers     = (const int*)d_in[3];
    const int*   graph_id      = (const int*)d_in[4];
    const float* species_embed = (const float*)d_in[5];
    const float* w_r1          = (const float*)d_in[6];
    const float* b_r1          = (const float*)d_in[7];
    const float* w_r2          = (const float*)d_in[8];
    const float* w_mix         = (const float*)d_in[9];
    const float* w_sc          = (const float*)d_in[10];
    const float* w_ro          = (const float*)d_in[11];
    const float* ln_gamma      = (const float*)d_in[12];
    const float* ln_beta       = (const float*)d_in[13];
    const float* w_h1          = (const float*)d_in[14];
    const float* b_h1          = (const float*)d_in[15];
    const float* w_h2          = (const float*)d_in[16];
    const float* b_h2          = (const float*)d_in[17];
    const float* scale         = (const float*)d_in[18];
    const float* shift         = (const float*)d_in[19];
    float* out = (float*)d_out;

    const int E = NE, N = NN, G = NG;

    // workspace layout (floats)
    float* ws    = (float*)d_ws;
    float* rw0_0 = ws;                              // E*32
    float* rw0_1 = rw0_0 + (size_t)E * 32;          // E*32
    float* hA    = rw0_1 + (size_t)E * 32;          // N*32
    float* hB    = hA + (size_t)N * 32;             // N*32
    float* agg   = hB + (size_t)N * 32;             // N*32
    float* gsum  = agg + (size_t)N * 32;            // G
    float* gcnt  = gsum + G;                        // G
    unsigned short* wt_hi = (unsigned short*)(gcnt + G);   // 4096
    unsigned short* wt_lo = wt_hi + 4096;                  // 4096

    prep_w_kernel<<<16, 256, 0, stream>>>(w_r2, wt_hi, wt_lo);
    init_h_kernel<<<(N * 32 + 255) / 256, 256, 0, stream>>>(node_species, species_embed, hA, N);

    edge_gemm_kernel<<<E / 256, 256, 0, stream>>>(
        vectors, w_r1, b_r1, wt_hi, wt_lo, rw0_0, rw0_1);

    float* hin = hA;
    float* hout = hB;
    const float* rw0s[2] = {rw0_0, rw0_1};
    for (int li = 0; li < 2; ++li) {
        hipMemsetAsync(agg, 0, (size_t)N * 32 * sizeof(float), stream);
        message_kernel<<<(E * 8) / 256, 256, 0, stream>>>(
            rw0s[li], hin, senders, receivers, agg, E);
        update_kernel<<<(N * 32 + 255) / 256, 256, 0, stream>>>(
            agg, hin, node_species, w_mix + li * 3072, w_sc + li * 65536, hout, N);
        float* tmp = hin; hin = hout; hout = tmp;
    }

    hipMemsetAsync(gsum, 0, (size_t)2 * G * sizeof(float), stream);
    readout_kernel<<<(N + 255) / 256, 256, 0, stream>>>(
        hin, graph_id, w_ro, ln_gamma, ln_beta, w_h1, b_h1, w_h2, b_h2, gsum, gcnt, N);
    finalize_kernel<<<1, 64, 0, stream>>>(gsum, gcnt, scale, shift, out, G);
}

// Round 3
// 169.616 us; speedup vs baseline: 2.1697x; 2.1697x over previous
//
#include <hip/hip_runtime.h>
#include <cstdint>
#include <cmath>

#define NE 320000
#define NN 20000
#define NG 64

typedef __attribute__((ext_vector_type(8))) short s16x8;
typedef __attribute__((ext_vector_type(4))) float f32x4;

static __device__ __forceinline__ unsigned short f32_to_bf16(float x) {
    unsigned int u = __float_as_uint(x);
    u = (u + 0x7fffu + ((u >> 16) & 1u)) >> 16;
    return (unsigned short)u;
}
static __device__ __forceinline__ float bf16_to_f32(unsigned short h) {
    return __uint_as_float(((unsigned int)h) << 16);
}

// ---------------------------------------------------------------------------
// Prep: transpose + bf16 hi/lo split of w_r2 m=0 slices, both layers.
// ---------------------------------------------------------------------------
__global__ __launch_bounds__(256) void prep_w_kernel(
    const float* __restrict__ w_r2,
    unsigned short* __restrict__ wt_hi, unsigned short* __restrict__ wt_lo)
{
    int t = blockIdx.x * 256 + threadIdx.x;   // 4096 entries
    int c = t >> 6, k = t & 63;
    float v = w_r2[(c >= 32 ? 6144 : 0) + k * 96 + (c & 31)];
    unsigned short hb = f32_to_bf16(v);
    float lov = v - bf16_to_f32(hb);
    wt_hi[t] = hb;
    wt_lo[t] = f32_to_bf16(lov);
}

// ---------------------------------------------------------------------------
// Fused edge kernel: bessel -> silu MLP -> (LDS bf16 hi/lo) -> MFMA GEMM
// ---------------------------------------------------------------------------
__global__ __launch_bounds__(256) void edge_gemm_kernel(
    const float* __restrict__ vectors,
    const float* __restrict__ w_r1,    // 8 x 64
    const float* __restrict__ b_r1,    // 64
    const unsigned short* __restrict__ wt_hi,  // [64][64] bf16
    const unsigned short* __restrict__ wt_lo,  // [64][64] bf16
    float* __restrict__ rw0_0,         // [E][32]
    float* __restrict__ rw0_1)         // [E][32]
{
    __shared__ __attribute__((aligned(16))) short sh_hi[256 * 72];
    __shared__ __attribute__((aligned(16))) short sh_lo[256 * 72];

    const int tid = threadIdx.x;
    const int e = blockIdx.x * 256 + tid;

    float x = vectors[3 * e + 0];
    float y = vectors[3 * e + 1];
    float z = vectors[3 * e + 2];
    float r2 = x * x + y * y + z * z;
    float r = (r2 == 0.0f) ? 0.0f : sqrtf(r2);
    float rs = fmaxf(r, 1e-6f);
    float u = fminf(r * 0.2f, 1.0f);
    float env = (1.0f - u) * (1.0f - u) * (1.0f + 2.0f * u);
    float pref = 0.6324555320336759f * env / rs;
    float theta = 0.6283185307179586f * rs;

    float s1 = __sinf(theta), c1 = __cosf(theta);
    float twoc = 2.0f * c1;
    float b[8];
    {
        float sp = 0.0f, s = s1;
#pragma unroll
        for (int n = 0; n < 8; ++n) {
            b[n] = pref * s;
            float nx = twoc * s - sp;
            sp = s; s = nx;
        }
    }

#pragma unroll
    for (int j0 = 0; j0 < 64; j0 += 8) {
        short hibuf[8], lobuf[8];
#pragma unroll
        for (int jj = 0; jj < 8; ++jj) {
            int j = j0 + jj;
            float pre = b_r1[j];
#pragma unroll
            for (int n = 0; n < 8; ++n) pre = fmaf(b[n], w_r1[n * 64 + j], pre);
            float rj = pre * __builtin_amdgcn_rcpf(1.0f + __expf(-pre));
            unsigned short hb = f32_to_bf16(rj);
            float lov = rj - bf16_to_f32(hb);
            hibuf[jj] = (short)hb;
            lobuf[jj] = (short)f32_to_bf16(lov);
        }
        *(s16x8*)&sh_hi[tid * 72 + j0] =
            (s16x8){hibuf[0],hibuf[1],hibuf[2],hibuf[3],hibuf[4],hibuf[5],hibuf[6],hibuf[7]};
        *(s16x8*)&sh_lo[tid * 72 + j0] =
            (s16x8){lobuf[0],lobuf[1],lobuf[2],lobuf[3],lobuf[4],lobuf[5],lobuf[6],lobuf[7]};
    }

    __syncthreads();

    const int wv = tid >> 6;
    const int l = tid & 63;
    const int lrow = l & 15;
    const int lk = l >> 4;

    s16x8 Bhi[4][2], Blo[4][2];
#pragma unroll
    for (int ct = 0; ct < 4; ++ct)
#pragma unroll
        for (int kt = 0; kt < 2; ++kt) {
            int col = ct * 16 + lrow;
            int kof = kt * 32 + lk * 8;
            Bhi[ct][kt] = *(const s16x8*)(wt_hi + col * 64 + kof);
            Blo[ct][kt] = *(const s16x8*)(wt_lo + col * 64 + kof);
        }

    f32x4 acc[4][4];
#pragma unroll
    for (int rt = 0; rt < 4; ++rt)
#pragma unroll
        for (int ct = 0; ct < 4; ++ct) acc[rt][ct] = (f32x4){0.f, 0.f, 0.f, 0.f};

#pragma unroll
    for (int rt = 0; rt < 4; ++rt) {
        int row = wv * 64 + rt * 16 + lrow;
#pragma unroll
        for (int kt = 0; kt < 2; ++kt) {
            s16x8 ahi = *(const s16x8*)&sh_hi[row * 72 + kt * 32 + lk * 8];
            s16x8 alo = *(const s16x8*)&sh_lo[row * 72 + kt * 32 + lk * 8];
#pragma unroll
            for (int ct = 0; ct < 4; ++ct) {
                acc[rt][ct] = __builtin_amdgcn_mfma_f32_16x16x32_bf16(ahi, Bhi[ct][kt], acc[rt][ct], 0, 0, 0);
                acc[rt][ct] = __builtin_amdgcn_mfma_f32_16x16x32_bf16(alo, Bhi[ct][kt], acc[rt][ct], 0, 0, 0);
                acc[rt][ct] = __builtin_amdgcn_mfma_f32_16x16x32_bf16(ahi, Blo[ct][kt], acc[rt][ct], 0, 0, 0);
            }
        }
    }

#pragma unroll
    for (int rt = 0; rt < 4; ++rt) {
#pragma unroll
        for (int ct = 0; ct < 4; ++ct) {
            int ebase = blockIdx.x * 256 + wv * 64 + rt * 16 + lk * 4;
            int col = ct * 16 + lrow;
            float* base = (col < 32) ? (rw0_0 + col) : (rw0_1 + (col - 32));
#pragma unroll
            for (int rr = 0; rr < 4; ++rr)
                base[(size_t)(ebase + rr) * 32] = acc[rt][ct][rr];
        }
    }
}

// ---------------------------------------------------------------------------
__global__ __launch_bounds__(256) void init_h_kernel(
    const int* __restrict__ spec, const float* __restrict__ emb,
    float* __restrict__ h, int N)
{
    int t = blockIdx.x * 256 + threadIdx.x;
    if (t >= N * 32) return;
    int n = t >> 5, c = t & 31;
    h[t] = emb[spec[n] * 32 + c];
}

// ---------------------------------------------------------------------------
// CSR build: count -> scan (2-level) -> scatter (edge, sender) pairs.
// ---------------------------------------------------------------------------
__global__ __launch_bounds__(256) void count_kernel(
    const int* __restrict__ recv, int* __restrict__ deg, int E)
{
    int e = blockIdx.x * 256 + threadIdx.x;
    if (e < E) atomicAdd(&deg[recv[e]], 1);
}

__global__ __launch_bounds__(256) void scanA_kernel(
    const int* __restrict__ deg, int* __restrict__ scanned,
    int* __restrict__ bsum, int N)
{
    __shared__ int lds[256];
    int tid = threadIdx.x;
    int i = blockIdx.x * 256 + tid;
    int v = (i < N) ? deg[i] : 0;
    lds[tid] = v;
    __syncthreads();
    for (int off = 1; off < 256; off <<= 1) {
        int t = (tid >= off) ? lds[tid - off] : 0;
        __syncthreads();
        lds[tid] += t;
        __syncthreads();
    }
    if (i < N) scanned[i] = lds[tid] - v;   // exclusive
    if (tid == 255) bsum[blockIdx.x] = lds[tid];
}

__global__ void scanB_kernel(int* __restrict__ bsum, int nb)
{
    if (threadIdx.x == 0) {
        int acc = 0;
        for (int b = 0; b < nb; ++b) { int t = bsum[b]; bsum[b] = acc; acc += t; }
    }
}

__global__ __launch_bounds__(256) void scanC_kernel(
    const int* __restrict__ scanned, const int* __restrict__ bsum,
    int* __restrict__ rowstart, int* __restrict__ cursor, int N, int E)
{
    int i = blockIdx.x * 256 + threadIdx.x;
    if (i < N) {
        int rs = scanned[i] + bsum[blockIdx.x];
        rowstart[i] = rs;
        cursor[i] = rs;
    }
    if (i == 0) rowstart[N] = E;
}

__global__ __launch_bounds__(256) void scatter_kernel(
    const int* __restrict__ recv, const int* __restrict__ snd,
    int* __restrict__ cursor, int2* __restrict__ eids, int E)
{
    int e = blockIdx.x * 256 + threadIdx.x;
    if (e < E) {
        int slot = atomicAdd(&cursor[recv[e]], 1);
        eids[slot] = make_int2(e, snd[e]);
    }
}

// ---------------------------------------------------------------------------
// Fused aggregate (CSR gather) + node update.
// thread = (node, channel c). Half-wave (32 lanes) = one node's full row.
// agg[c] = sum_edges rw0[e][c]*h[snd][c]; then via shfl:
// h_out[n][c] = h[n][c] + sum_c' agg[c']*w_mix0[c'][c] + sum_c' h[n][c']*w_sc[s][c'][c]
// ---------------------------------------------------------------------------
__global__ __launch_bounds__(256) void agg_update_kernel(
    const float* __restrict__ rw0, const float* __restrict__ h_in,
    const int* __restrict__ rowstart, const int2* __restrict__ eids,
    const int* __restrict__ spec,
    const float* __restrict__ w_mix0,  // 32 x 32
    const float* __restrict__ w_sc_l,  // 64 x 32 x 32
    float* __restrict__ h_out, int N)
{
    int t = blockIdx.x * 256 + threadIdx.x;   // grid sized exactly N*32
    int n = t >> 5, c = t & 31;
    int lane = threadIdx.x & 63;
    int half = lane & 32;

    int s0 = rowstart[n], s1 = rowstart[n + 1];
    float acc = 0.0f;
    int k = s0;
    for (; k + 1 < s1; k += 2) {
        int2 a = eids[k];
        int2 b = eids[k + 1];
        float r1 = rw0[(size_t)a.x * 32 + c];
        float h1 = h_in[(size_t)a.y * 32 + c];
        float r2 = rw0[(size_t)b.x * 32 + c];
        float h2 = h_in[(size_t)b.y * 32 + c];
        acc = fmaf(r1, h1, acc);
        acc = fmaf(r2, h2, acc);
    }
    if (k < s1) {
        int2 a = eids[k];
        acc = fmaf(rw0[(size_t)a.x * 32 + c], h_in[(size_t)a.y * 32 + c], acc);
    }

    float hv = h_in[t];
    int sp = spec[n];
    const float* wsc = w_sc_l + sp * 1024;
    float outv = hv;
#pragma unroll
    for (int cp = 0; cp < 32; ++cp) {
        float av  = __shfl(acc, half + cp);
        float hvb = __shfl(hv,  half + cp);
        outv = fmaf(av,  w_mix0[cp * 32 + c], outv);
        outv = fmaf(hvb, wsc[cp * 32 + c], outv);
    }
    h_out[t] = outv;
}

// ---------------------------------------------------------------------------
__global__ __launch_bounds__(256) void readout_kernel(
    const float* __restrict__ h, const int* __restrict__ gid_arr,
    const float* __restrict__ w_ro,
    const float* __restrict__ gamma, const float* __restrict__ beta,
    const float* __restrict__ w_h1, const float* __restrict__ b_h1,
    const float* __restrict__ w_h2, const float* __restrict__ b_h2,
    float* __restrict__ gsum, float* __restrict__ gcnt, int N)
{
    int t = blockIdx.x * 256 + threadIdx.x;
    int lane = threadIdx.x & 63;
    bool active = t < N;

    float val = 0.0f;
    int gid = -1;
    if (active) {
        gid = gid_arr[t];
        const float* hr = h + (size_t)t * 32;
        float ro[16];
#pragma unroll
        for (int o = 0; o < 16; ++o) ro[o] = 0.0f;
#pragma unroll
        for (int c = 0; c < 32; ++c) {
            float hv = hr[c];
#pragma unroll
            for (int o = 0; o < 16; ++o) ro[o] = fmaf(hv, w_ro[c * 16 + o], ro[o]);
        }
        float mu = 0.0f;
#pragma unroll
        for (int o = 0; o < 16; ++o) mu += ro[o];
        mu *= (1.0f / 16.0f);
        float var = 0.0f;
#pragma unroll
        for (int o = 0; o < 16; ++o) { float d = ro[o] - mu; var = fmaf(d, d, var); }
        var *= (1.0f / 16.0f);
        float inv = rsqrtf(var + 1e-6f);
        float nrm[16];
#pragma unroll
        for (int o = 0; o < 16; ++o) nrm[o] = (ro[o] - mu) * inv * gamma[o] + beta[o];

        float outv = b_h2[0];
        for (int j = 0; j < 64; ++j) {
            float a = b_h1[j];
#pragma unroll
            for (int o = 0; o < 16; ++o) a = fmaf(nrm[o], w_h1[o * 64 + j], a);
            float g = 0.5f * a * (1.0f + tanhf(0.7978845608028654f * (a + 0.044715f * a * a * a)));
            outv = fmaf(g, w_h2[j], outv);
        }
        val = outv;
    }
    float cval = active ? 1.0f : 0.0f;

#pragma unroll
    for (int off = 1; off < 64; off <<= 1) {
        float v = __shfl_down(val, off);
        float cv = __shfl_down(cval, off);
        int g = __shfl_down(gid, off);
        if (lane + off < 64 && g == gid) { val += v; cval += cv; }
    }
    int gprev = __shfl_up(gid, 1);
    bool head = (lane == 0) || (gprev != gid);
    if (active && head) {
        atomicAdd(&gsum[gid], val);
        atomicAdd(&gcnt[gid], cval);
    }
}

// ---------------------------------------------------------------------------
__global__ void finalize_kernel(const float* __restrict__ gsum,
                                const float* __restrict__ gcnt,
                                const float* __restrict__ scale,
                                const float* __restrict__ shift,
                                float* __restrict__ out, int G)
{
    int g = blockIdx.x * blockDim.x + threadIdx.x;
    if (g < G) out[g] = gsum[g] / fmaxf(gcnt[g], 1.0f) * scale[0] + shift[0];
}

// ---------------------------------------------------------------------------
extern "C" void kernel_launch(void* const* d_in, const int* in_sizes, int n_in,
                              void* d_out, int out_size, void* d_ws, size_t ws_size,
                              hipStream_t stream)
{
    const float* vectors       = (const float*)d_in[0];
    const int*   node_species  = (const int*)d_in[1];
    const int*   senders       = (const int*)d_in[2];
    const int*   receivers     = (const int*)d_in[3];
    const int*   graph_id      = (const int*)d_in[4];
    const float* species_embed = (const float*)d_in[5];
    const float* w_r1          = (const float*)d_in[6];
    const float* b_r1          = (const float*)d_in[7];
    const float* w_r2          = (const float*)d_in[8];
    const float* w_mix         = (const float*)d_in[9];
    const float* w_sc          = (const float*)d_in[10];
    const float* w_ro          = (const float*)d_in[11];
    const float* ln_gamma      = (const float*)d_in[12];
    const float* ln_beta       = (const float*)d_in[13];
    const float* w_h1          = (const float*)d_in[14];
    const float* b_h1          = (const float*)d_in[15];
    const float* w_h2          = (const float*)d_in[16];
    const float* b_h2          = (const float*)d_in[17];
    const float* scale         = (const float*)d_in[18];
    const float* shift         = (const float*)d_in[19];
    float* out = (float*)d_out;

    const int E = NE, N = NN, G = NG;
    const int NB = (N + 255) / 256;   // 79 scan blocks

    // workspace layout
    float* ws    = (float*)d_ws;
    float* rw0_0 = ws;                              // E*32
    float* rw0_1 = rw0_0 + (size_t)E * 32;          // E*32
    float* hA    = rw0_1 + (size_t)E * 32;          // N*32
    float* hB    = hA + (size_t)N * 32;             // N*32
    float* gsum  = hB + (size_t)N * 32;             // G
    float* gcnt  = gsum + G;                        // G
    unsigned short* wt_hi = (unsigned short*)(gcnt + G);   // 4096
    unsigned short* wt_lo = wt_hi + 4096;                  // 4096
    int* deg      = (int*)(wt_lo + 4096);           // N
    int* scanned  = deg + N;                        // N
    int* bsum     = scanned + N;                    // NB (pad 128)
    int* rowstart = bsum + 128;                     // N+1
    int* cursor   = rowstart + N + 1;               // N
    int2* eids    = (int2*)(cursor + N + 1);        // E

    // --- CSR build (receivers static across layers) ---
    hipMemsetAsync(deg, 0, (size_t)N * sizeof(int), stream);
    count_kernel<<<(E + 255) / 256, 256, 0, stream>>>(receivers, deg, E);
    scanA_kernel<<<NB, 256, 0, stream>>>(deg, scanned, bsum, N);
    scanB_kernel<<<1, 64, 0, stream>>>(bsum, NB);
    scanC_kernel<<<NB, 256, 0, stream>>>(scanned, bsum, rowstart, cursor, N, E);
    scatter_kernel<<<(E + 255) / 256, 256, 0, stream>>>(receivers, senders, cursor, eids, E);

    prep_w_kernel<<<16, 256, 0, stream>>>(w_r2, wt_hi, wt_lo);
    init_h_kernel<<<(N * 32 + 255) / 256, 256, 0, stream>>>(node_species, species_embed, hA, N);

    edge_gemm_kernel<<<E / 256, 256, 0, stream>>>(
        vectors, w_r1, b_r1, wt_hi, wt_lo, rw0_0, rw0_1);

    float* hin = hA;
    float* hout = hB;
    const float* rw0s[2] = {rw0_0, rw0_1};
    for (int li = 0; li < 2; ++li) {
        agg_update_kernel<<<(N * 32) / 256, 256, 0, stream>>>(
            rw0s[li], hin, rowstart, eids, node_species,
            w_mix + li * 3072, w_sc + li * 65536, hout, N);
        float* tmp = hin; hin = hout; hout = tmp;
    }

    hipMemsetAsync(gsum, 0, (size_t)2 * G * sizeof(float), stream);
    readout_kernel<<<(N + 255) / 256, 256, 0, stream>>>(
        hin, graph_id, w_ro, ln_gamma, ln_beta, w_h1, b_h1, w_h2, b_h2, gsum, gcnt, N);
    finalize_kernel<<<1, 64, 0, stream>>>(gsum, gcnt, scale, shift, out, G);
}

// Round 4
// 156.182 us; speedup vs baseline: 2.3563x; 1.0860x over previous
//
#include <hip/hip_runtime.h>
#include <cstdint>
#include <cmath>

#define NE 320000
#define NN 20000
#define NG 64

typedef __attribute__((ext_vector_type(8))) short s16x8;
typedef __attribute__((ext_vector_type(4))) float f32x4;

static __device__ __forceinline__ unsigned short f32_to_bf16(float x) {
    unsigned int u = __float_as_uint(x);
    u = (u + 0x7fffu + ((u >> 16) & 1u)) >> 16;
    return (unsigned short)u;
}
static __device__ __forceinline__ float bf16_to_f32(unsigned short h) {
    return __uint_as_float(((unsigned int)h) << 16);
}

// ---------------------------------------------------------------------------
// Fused setup: init_h (N*32), prep_w (4096), zero deg (N), zero gsum/gcnt (128)
// grid = 2500 x 256 covers N*32 = 640000
// ---------------------------------------------------------------------------
__global__ __launch_bounds__(256) void setup_kernel(
    const int* __restrict__ spec, const float* __restrict__ emb,
    float* __restrict__ h,
    const float* __restrict__ w_r2,
    unsigned short* __restrict__ wt_hi, unsigned short* __restrict__ wt_lo,
    int* __restrict__ deg, float* __restrict__ gzero, int N)
{
    int t = blockIdx.x * 256 + threadIdx.x;
    if (t < N * 32) h[t] = emb[spec[t >> 5] * 32 + (t & 31)];
    if (t < 4096) {
        int c = t >> 6, k = t & 63;
        float v = w_r2[(c >= 32 ? 6144 : 0) + k * 96 + (c & 31)];
        unsigned short hb = f32_to_bf16(v);
        wt_hi[t] = hb;
        wt_lo[t] = f32_to_bf16(v - bf16_to_f32(hb));
    }
    if (t < N) deg[t] = 0;
    if (t < 128) gzero[t] = 0.0f;
}

// ---------------------------------------------------------------------------
// Fused edge kernel: bessel -> silu MLP -> (LDS bf16 hi/lo) -> MFMA GEMM
// ---------------------------------------------------------------------------
__global__ __launch_bounds__(256) void edge_gemm_kernel(
    const float* __restrict__ vectors,
    const float* __restrict__ w_r1,    // 8 x 64
    const float* __restrict__ b_r1,    // 64
    const unsigned short* __restrict__ wt_hi,  // [64][64] bf16
    const unsigned short* __restrict__ wt_lo,  // [64][64] bf16
    float* __restrict__ rw0_0,         // [E][32]
    float* __restrict__ rw0_1)         // [E][32]
{
    __shared__ __attribute__((aligned(16))) short sh_hi[256 * 72];
    __shared__ __attribute__((aligned(16))) short sh_lo[256 * 72];

    const int tid = threadIdx.x;
    const int e = blockIdx.x * 256 + tid;

    float x = vectors[3 * e + 0];
    float y = vectors[3 * e + 1];
    float z = vectors[3 * e + 2];
    float r2 = x * x + y * y + z * z;
    float r = (r2 == 0.0f) ? 0.0f : sqrtf(r2);
    float rs = fmaxf(r, 1e-6f);
    float u = fminf(r * 0.2f, 1.0f);
    float env = (1.0f - u) * (1.0f - u) * (1.0f + 2.0f * u);
    float pref = 0.6324555320336759f * env / rs;
    float theta = 0.6283185307179586f * rs;

    float s1 = __sinf(theta), c1 = __cosf(theta);
    float twoc = 2.0f * c1;
    float b[8];
    {
        float sp = 0.0f, s = s1;
#pragma unroll
        for (int n = 0; n < 8; ++n) {
            b[n] = pref * s;
            float nx = twoc * s - sp;
            sp = s; s = nx;
        }
    }

#pragma unroll
    for (int j0 = 0; j0 < 64; j0 += 8) {
        short hibuf[8], lobuf[8];
#pragma unroll
        for (int jj = 0; jj < 8; ++jj) {
            int j = j0 + jj;
            float pre = b_r1[j];
#pragma unroll
            for (int n = 0; n < 8; ++n) pre = fmaf(b[n], w_r1[n * 64 + j], pre);
            float rj = pre * __builtin_amdgcn_rcpf(1.0f + __expf(-pre));
            unsigned short hb = f32_to_bf16(rj);
            float lov = rj - bf16_to_f32(hb);
            hibuf[jj] = (short)hb;
            lobuf[jj] = (short)f32_to_bf16(lov);
        }
        *(s16x8*)&sh_hi[tid * 72 + j0] =
            (s16x8){hibuf[0],hibuf[1],hibuf[2],hibuf[3],hibuf[4],hibuf[5],hibuf[6],hibuf[7]};
        *(s16x8*)&sh_lo[tid * 72 + j0] =
            (s16x8){lobuf[0],lobuf[1],lobuf[2],lobuf[3],lobuf[4],lobuf[5],lobuf[6],lobuf[7]};
    }

    __syncthreads();

    const int wv = tid >> 6;
    const int l = tid & 63;
    const int lrow = l & 15;
    const int lk = l >> 4;

    s16x8 Bhi[4][2], Blo[4][2];
#pragma unroll
    for (int ct = 0; ct < 4; ++ct)
#pragma unroll
        for (int kt = 0; kt < 2; ++kt) {
            int col = ct * 16 + lrow;
            int kof = kt * 32 + lk * 8;
            Bhi[ct][kt] = *(const s16x8*)(wt_hi + col * 64 + kof);
            Blo[ct][kt] = *(const s16x8*)(wt_lo + col * 64 + kof);
        }

    f32x4 acc[4][4];
#pragma unroll
    for (int rt = 0; rt < 4; ++rt)
#pragma unroll
        for (int ct = 0; ct < 4; ++ct) acc[rt][ct] = (f32x4){0.f, 0.f, 0.f, 0.f};

#pragma unroll
    for (int rt = 0; rt < 4; ++rt) {
        int row = wv * 64 + rt * 16 + lrow;
#pragma unroll
        for (int kt = 0; kt < 2; ++kt) {
            s16x8 ahi = *(const s16x8*)&sh_hi[row * 72 + kt * 32 + lk * 8];
            s16x8 alo = *(const s16x8*)&sh_lo[row * 72 + kt * 32 + lk * 8];
#pragma unroll
            for (int ct = 0; ct < 4; ++ct) {
                acc[rt][ct] = __builtin_amdgcn_mfma_f32_16x16x32_bf16(ahi, Bhi[ct][kt], acc[rt][ct], 0, 0, 0);
                acc[rt][ct] = __builtin_amdgcn_mfma_f32_16x16x32_bf16(alo, Bhi[ct][kt], acc[rt][ct], 0, 0, 0);
                acc[rt][ct] = __builtin_amdgcn_mfma_f32_16x16x32_bf16(ahi, Blo[ct][kt], acc[rt][ct], 0, 0, 0);
            }
        }
    }

#pragma unroll
    for (int rt = 0; rt < 4; ++rt) {
#pragma unroll
        for (int ct = 0; ct < 4; ++ct) {
            int ebase = blockIdx.x * 256 + wv * 64 + rt * 16 + lk * 4;
            int col = ct * 16 + lrow;
            float* base = (col < 32) ? (rw0_0 + col) : (rw0_1 + (col - 32));
#pragma unroll
            for (int rr = 0; rr < 4; ++rr)
                base[(size_t)(ebase + rr) * 32] = acc[rt][ct][rr];
        }
    }
}

// ---------------------------------------------------------------------------
// CSR build: count -> scan (2-level, parallel) -> scatter (edge,sender) pairs.
// ---------------------------------------------------------------------------
__global__ __launch_bounds__(256) void count_kernel(
    const int* __restrict__ recv, int* __restrict__ deg, int E)
{
    int e = blockIdx.x * 256 + threadIdx.x;
    if (e < E) atomicAdd(&deg[recv[e]], 1);
}

__global__ __launch_bounds__(256) void scanA_kernel(
    const int* __restrict__ deg, int* __restrict__ scanned,
    int* __restrict__ bsum, int N)
{
    __shared__ int lds[256];
    int tid = threadIdx.x;
    int i = blockIdx.x * 256 + tid;
    int v = (i < N) ? deg[i] : 0;
    lds[tid] = v;
    __syncthreads();
    for (int off = 1; off < 256; off <<= 1) {
        int t = (tid >= off) ? lds[tid - off] : 0;
        __syncthreads();
        lds[tid] += t;
        __syncthreads();
    }
    if (i < N) scanned[i] = lds[tid] - v;   // exclusive
    if (tid == 255) bsum[blockIdx.x] = lds[tid];
}

// parallel scan of up to 128 block sums (1 block, 128 threads = 2 waves)
__global__ __launch_bounds__(128) void scanB_kernel(int* __restrict__ bsum, int nb)
{
    __shared__ int wtot;
    int tid = threadIdx.x;
    int lane = tid & 63;
    int orig = (tid < nb) ? bsum[tid] : 0;
    int v = orig;
#pragma unroll
    for (int off = 1; off < 64; off <<= 1) {
        int u = __shfl_up(v, off);
        if (lane >= off) v += u;
    }
    if (tid == 63) wtot = v;
    __syncthreads();
    if (tid >= 64) v += wtot;
    if (tid < nb) bsum[tid] = v - orig;   // exclusive
}

__global__ __launch_bounds__(256) void scanC_kernel(
    const int* __restrict__ scanned, const int* __restrict__ bsum,
    int* __restrict__ rowstart, int* __restrict__ cursor, int N, int E)
{
    int i = blockIdx.x * 256 + threadIdx.x;
    if (i < N) {
        int rs = scanned[i] + bsum[blockIdx.x];
        rowstart[i] = rs;
        cursor[i] = rs;
    }
    if (i == 0) rowstart[N] = E;
}

__global__ __launch_bounds__(256) void scatter_kernel(
    const int* __restrict__ recv, const int* __restrict__ snd,
    int* __restrict__ cursor, int2* __restrict__ eids, int E)
{
    int e = blockIdx.x * 256 + threadIdx.x;
    if (e < E) {
        int slot = atomicAdd(&cursor[recv[e]], 1);
        eids[slot] = make_int2(e, snd[e]);
    }
}

// ---------------------------------------------------------------------------
// Fused aggregate (CSR gather) + node update.
// ---------------------------------------------------------------------------
__global__ __launch_bounds__(256) void agg_update_kernel(
    const float* __restrict__ rw0, const float* __restrict__ h_in,
    const int* __restrict__ rowstart, const int2* __restrict__ eids,
    const int* __restrict__ spec,
    const float* __restrict__ w_mix0,  // 32 x 32
    const float* __restrict__ w_sc_l,  // 64 x 32 x 32
    float* __restrict__ h_out, int N)
{
    int t = blockIdx.x * 256 + threadIdx.x;   // grid = N*32 exactly
    int n = t >> 5, c = t & 31;
    int lane = threadIdx.x & 63;
    int half = lane & 32;

    int s0 = rowstart[n], s1 = rowstart[n + 1];
    float acc = 0.0f;
    int k = s0;
    for (; k + 1 < s1; k += 2) {
        int2 a = eids[k];
        int2 b = eids[k + 1];
        float r1 = rw0[(size_t)a.x * 32 + c];
        float h1 = h_in[(size_t)a.y * 32 + c];
        float r2 = rw0[(size_t)b.x * 32 + c];
        float h2 = h_in[(size_t)b.y * 32 + c];
        acc = fmaf(r1, h1, acc);
        acc = fmaf(r2, h2, acc);
    }
    if (k < s1) {
        int2 a = eids[k];
        acc = fmaf(rw0[(size_t)a.x * 32 + c], h_in[(size_t)a.y * 32 + c], acc);
    }

    float hv = h_in[t];
    int sp = spec[n];
    const float* wsc = w_sc_l + sp * 1024;
    float outv = hv;
#pragma unroll
    for (int cp = 0; cp < 32; ++cp) {
        float av  = __shfl(acc, half + cp);
        float hvb = __shfl(hv,  half + cp);
        outv = fmaf(av,  w_mix0[cp * 32 + c], outv);
        outv = fmaf(hvb, wsc[cp * 32 + c], outv);
    }
    h_out[t] = outv;
}

// ---------------------------------------------------------------------------
__global__ __launch_bounds__(256) void readout_kernel(
    const float* __restrict__ h, const int* __restrict__ gid_arr,
    const float* __restrict__ w_ro,
    const float* __restrict__ gamma, const float* __restrict__ beta,
    const float* __restrict__ w_h1, const float* __restrict__ b_h1,
    const float* __restrict__ w_h2, const float* __restrict__ b_h2,
    float* __restrict__ gsum, float* __restrict__ gcnt, int N)
{
    int t = blockIdx.x * 256 + threadIdx.x;
    int lane = threadIdx.x & 63;
    bool active = t < N;

    float val = 0.0f;
    int gid = -1;
    if (active) {
        gid = gid_arr[t];
        const float* hr = h + (size_t)t * 32;
        float ro[16];
#pragma unroll
        for (int o = 0; o < 16; ++o) ro[o] = 0.0f;
#pragma unroll
        for (int c = 0; c < 32; ++c) {
            float hv = hr[c];
#pragma unroll
            for (int o = 0; o < 16; ++o) ro[o] = fmaf(hv, w_ro[c * 16 + o], ro[o]);
        }
        float mu = 0.0f;
#pragma unroll
        for (int o = 0; o < 16; ++o) mu += ro[o];
        mu *= (1.0f / 16.0f);
        float var = 0.0f;
#pragma unroll
        for (int o = 0; o < 16; ++o) { float d = ro[o] - mu; var = fmaf(d, d, var); }
        var *= (1.0f / 16.0f);
        float inv = rsqrtf(var + 1e-6f);
        float nrm[16];
#pragma unroll
        for (int o = 0; o < 16; ++o) nrm[o] = (ro[o] - mu) * inv * gamma[o] + beta[o];

        float outv = b_h2[0];
        for (int j = 0; j < 64; ++j) {
            float a = b_h1[j];
#pragma unroll
            for (int o = 0; o < 16; ++o) a = fmaf(nrm[o], w_h1[o * 64 + j], a);
            float g = 0.5f * a * (1.0f + tanhf(0.7978845608028654f * (a + 0.044715f * a * a * a)));
            outv = fmaf(g, w_h2[j], outv);
        }
        val = outv;
    }
    float cval = active ? 1.0f : 0.0f;

#pragma unroll
    for (int off = 1; off < 64; off <<= 1) {
        float v = __shfl_down(val, off);
        float cv = __shfl_down(cval, off);
        int g = __shfl_down(gid, off);
        if (lane + off < 64 && g == gid) { val += v; cval += cv; }
    }
    int gprev = __shfl_up(gid, 1);
    bool head = (lane == 0) || (gprev != gid);
    if (active && head) {
        atomicAdd(&gsum[gid], val);
        atomicAdd(&gcnt[gid], cval);
    }
}

// ---------------------------------------------------------------------------
__global__ void finalize_kernel(const float* __restrict__ gsum,
                                const float* __restrict__ gcnt,
                                const float* __restrict__ scale,
                                const float* __restrict__ shift,
                                float* __restrict__ out, int G)
{
    int g = blockIdx.x * blockDim.x + threadIdx.x;
    if (g < G) out[g] = gsum[g] / fmaxf(gcnt[g], 1.0f) * scale[0] + shift[0];
}

// ---------------------------------------------------------------------------
extern "C" void kernel_launch(void* const* d_in, const int* in_sizes, int n_in,
                              void* d_out, int out_size, void* d_ws, size_t ws_size,
                              hipStream_t stream)
{
    const float* vectors       = (const float*)d_in[0];
    const int*   node_species  = (const int*)d_in[1];
    const int*   senders       = (const int*)d_in[2];
    const int*   receivers     = (const int*)d_in[3];
    const int*   graph_id      = (const int*)d_in[4];
    const float* species_embed = (const float*)d_in[5];
    const float* w_r1          = (const float*)d_in[6];
    const float* b_r1          = (const float*)d_in[7];
    const float* w_r2          = (const float*)d_in[8];
    const float* w_mix         = (const float*)d_in[9];
    const float* w_sc          = (const float*)d_in[10];
    const float* w_ro          = (const float*)d_in[11];
    const float* ln_gamma      = (const float*)d_in[12];
    const float* ln_beta       = (const float*)d_in[13];
    const float* w_h1          = (const float*)d_in[14];
    const float* b_h1          = (const float*)d_in[15];
    const float* w_h2          = (const float*)d_in[16];
    const float* b_h2          = (const float*)d_in[17];
    const float* scale         = (const float*)d_in[18];
    const float* shift         = (const float*)d_in[19];
    float* out = (float*)d_out;

    const int E = NE, N = NN, G = NG;
    const int NB = (N + 255) / 256;   // 79 scan blocks

    // workspace layout
    float* ws    = (float*)d_ws;
    float* rw0_0 = ws;                              // E*32
    float* rw0_1 = rw0_0 + (size_t)E * 32;          // E*32
    float* hA    = rw0_1 + (size_t)E * 32;          // N*32
    float* hB    = hA + (size_t)N * 32;             // N*32
    float* gsum  = hB + (size_t)N * 32;             // G
    float* gcnt  = gsum + G;                        // G
    unsigned short* wt_hi = (unsigned short*)(gcnt + G);   // 4096
    unsigned short* wt_lo = wt_hi + 4096;                  // 4096
    int* deg      = (int*)(wt_lo + 4096);           // N
    int* scanned  = deg + N;                        // N
    int* bsum     = scanned + N;                    // NB (pad 128)
    int* rowstart = bsum + 128;                     // N+1
    int* cursor   = rowstart + N + 1;               // N
    int2* eids    = (int2*)(cursor + N + 1);        // E

    // fused init: h, wt_hi/lo, deg=0, gsum/gcnt=0
    setup_kernel<<<(N * 32 + 255) / 256, 256, 0, stream>>>(
        node_species, species_embed, hA, w_r2, wt_hi, wt_lo, deg, gsum, N);

    // CSR build (receivers static across layers)
    count_kernel<<<(E + 255) / 256, 256, 0, stream>>>(receivers, deg, E);
    scanA_kernel<<<NB, 256, 0, stream>>>(deg, scanned, bsum, N);
    scanB_kernel<<<1, 128, 0, stream>>>(bsum, NB);
    scanC_kernel<<<NB, 256, 0, stream>>>(scanned, bsum, rowstart, cursor, N, E);
    scatter_kernel<<<(E + 255) / 256, 256, 0, stream>>>(receivers, senders, cursor, eids, E);

    edge_gemm_kernel<<<E / 256, 256, 0, stream>>>(
        vectors, w_r1, b_r1, wt_hi, wt_lo, rw0_0, rw0_1);

    float* hin = hA;
    float* hout = hB;
    const float* rw0s[2] = {rw0_0, rw0_1};
    for (int li = 0; li < 2; ++li) {
        agg_update_kernel<<<(N * 32) / 256, 256, 0, stream>>>(
            rw0s[li], hin, rowstart, eids, node_species,
            w_mix + li * 3072, w_sc + li * 65536, hout, N);
        float* tmp = hin; hin = hout; hout = tmp;
    }

    readout_kernel<<<(N + 255) / 256, 256, 0, stream>>>(
        hin, graph_id, w_ro, ln_gamma, ln_beta, w_h1, b_h1, w_h2, b_h2, gsum, gcnt, N);
    finalize_kernel<<<1, 64, 0, stream>>>(gsum, gcnt, scale, shift, out, G);
}